// Round 1
// 476.708 us; speedup vs baseline: 1.3481x; 1.3481x over previous
//
#include <hip/hip_runtime.h>

typedef float f32x4 __attribute__((ext_vector_type(4)));
typedef __bf16 bf16x4 __attribute__((ext_vector_type(4)));
typedef __bf16 bf16x8 __attribute__((ext_vector_type(8)));
typedef short s16x4 __attribute__((ext_vector_type(4)));

#define DEVI static __device__ __forceinline__

DEVI f32x4 mfma_k32(bf16x8 a, bf16x8 b, f32x4 c) {
    return __builtin_amdgcn_mfma_f32_16x16x32_bf16(a, b, c, 0, 0, 0);
}

union B4 { bf16x4 h; s16x4 s; };
// 16x16x16 bf16 MFMA: A/B frag k-index = (lane>>4)*4+j == C/D reg layout -> lane-local refragment
DEVI f32x4 mfma_k16(bf16x4 a, bf16x4 b, f32x4 c) {
    B4 ua, ub; ua.h = a; ub.h = b;
    return __builtin_amdgcn_mfma_f32_16x16x16bf16_1k(ua.s, ub.s, c, 0, 0, 0);
}

union F8 { bf16x8 v; bf16x4 h[2]; };

DEVI bf16x8 ld8_lds(const __bf16* p) {   // 16B fragment from LDS (two b64 reads)
    F8 f;
    f.h[0] = *(const bf16x4*)p;
    f.h[1] = *(const bf16x4*)(p + 4);
    return f.v;
}
DEVI bf16x8 ld8_gb(const __bf16* p) { return *(const bf16x8*)p; }  // 16B global
DEVI bf16x8 ldf8(const float* p) {       // 8 fp32 -> bf16x8
    f32x4 a = *(const f32x4*)p;
    f32x4 b = *(const f32x4*)(p + 4);
    F8 f;
#pragma unroll
    for (int j = 0; j < 4; ++j) {
        f.h[0][j] = (__bf16)a[j];
        f.h[1][j] = (__bf16)b[j];
    }
    return f.v;
}

// ---- pre-kernel: weights fp32 -> bf16, re-tiled into MFMA-fragment order ----
// layout: tile t (16 rows), kc (8 k-chunks of 32), lane l (64), j (8):
//   elem = W[t*16 + (l&15)][kc*32 + (l>>4)*8 + j]  -> flat ((t*8+kc)*64+l)*8+j
// tiles 0..47 = qkv rows 0..767, tiles 48..63 = proj rows 0..255.
__global__ __launch_bounds__(256) void k_w2bf(const float* __restrict__ wqkv,
                                              const float* __restrict__ wp,
                                              __bf16* __restrict__ o) {
    int i = blockIdx.x * 256 + threadIdx.x;      // 32768 threads, one per (t,kc,l)
    int t = i >> 9, kc = (i >> 6) & 7, l = i & 63;
    int row = t * 16 + (l & 15);
    int col = kc * 32 + (l >> 4) * 8;
    const float* src = (t < 48) ? (wqkv + row * 256 + col)
                                : (wp + (row - 768) * 256 + col);
    f32x4 a = *(const f32x4*)src;
    f32x4 b = *(const f32x4*)(src + 4);
    F8 f;
#pragma unroll
    for (int j = 0; j < 4; ++j) { f.h[0][j] = (__bf16)a[j]; f.h[1][j] = (__bf16)b[j]; }
    *(bf16x8*)(o + (size_t)i * 8) = f.v;
}

// ---------------------------------------------------------------------------
// Fused shifted-window attention. 1 block = 1 window, 8 waves = 8 heads.
// Only 2 barriers per block; attention fully register-resident per wave.
// ---------------------------------------------------------------------------
__global__ __launch_bounds__(512, 4) void k_swin(
    const float* __restrict__ x,      // [32,56,56,256] fp32
    const __bf16* __restrict__ wb,    // tiled weights (ws): 64 tiles x 4096
    const float* __restrict__ bqkv,   // [768]
    const float* __restrict__ btab,   // [169,8]
    const float* __restrict__ pbias,  // [256]
    float* __restrict__ out)          // [32,56,56,256] fp32
{
    __shared__ __align__(16) unsigned char smem[53936];
    __bf16* xw = (__bf16*)(smem);                 // [49][260] staged window (bf16)
    __bf16* cb = (__bf16*)(smem + 25480);         // [49][260] ctx (attn output)
    __bf16* tb = (__bf16*)(smem + 50960);         // [8][170] bias table (transposed)
    unsigned* tinfo = (unsigned*)(smem + 53680);  // [64] token code|grp

    const int tid = threadIdx.x;
    const int wid = tid >> 6, lane = tid & 63;
    const int li = lane & 15, g = lane >> 4;
    const int blk = blockIdx.x;
    const int b = blk >> 6, wi = blk & 63;
    const int wh = wi >> 3, ww = wi & 7;
    const int h = wid;                            // wave == head

    // ---- stage shifted window (fp32 -> bf16) ----
    for (int c = tid; c < 49 * 32; c += 512) {
        int tok = c >> 5, part = c & 31;
        int i = tok / 7, j = tok - 7 * i;
        int r = wh * 7 + i + 3;  if (r >= 56) r -= 56;
        int cc = ww * 7 + j + 3; if (cc >= 56) cc -= 56;
        F8 f; f.v = ldf8(x + (((size_t)(b * 56 + r) * 56 + cc) << 8) + (part << 3));
        __bf16* dst = xw + tok * 260 + (part << 3);
        *(bf16x4*)dst = f.h[0];
        *(bf16x4*)(dst + 4) = f.h[1];
    }
    for (int c = tid; c < 169 * 8; c += 512) {       // bias table, transposed
        int idx = c >> 3, hh = c & 7;
        tb[hh * 170 + idx] = (__bf16)btab[c];
    }
    if (tid < 64) {
        int tok = tid;
        if (tok < 49) {
            int i = tok / 7, j = tok - 7 * i;
            unsigned rh = (wh == 7) ? (i < 4 ? 1u : 2u) : 0u;
            unsigned rw = (ww == 7) ? (j < 4 ? 1u : 2u) : 0u;
            tinfo[tok] = (unsigned)(13 * i + j) | ((rh * 3u + rw) << 16);
        } else {
            tinfo[tok] = 255u << 16;
        }
    }
    __syncthreads();   // barrier #1 (xw/tb/tinfo ready; read-only afterwards)

    const f32x4 zf = {0.f, 0.f, 0.f, 0.f};

    // ---- Q,K GEMM (head h): Q^T/K^T = W . X^T, A=W rows=out-ch, B=x rows=tok
    // acc[ct][tt]: lane holds ch = 16ct+4g+r, tok = 16tt+li
    f32x4 qa[2][4], ka[2][4];
#pragma unroll
    for (int ct = 0; ct < 2; ++ct)
#pragma unroll
        for (int tt = 0; tt < 4; ++tt) { qa[ct][tt] = zf; ka[ct][tt] = zf; }

    const __bf16* wqb = wb + (size_t)(2 * h) * 4096 + lane * 8;  // q tiles 2h,2h+1
    const __bf16* wkb = wqb + 16 * 4096;                          // k tiles +16
    const __bf16* wvb = wqb + 32 * 4096;                          // v tiles +32

#pragma unroll
    for (int kc = 0; kc < 8; ++kc) {
        bf16x8 xf[4];
#pragma unroll
        for (int tt = 0; tt < 4; ++tt) {
            int row = 16 * tt + li; if (row > 48) row = 48;   // clamp pad rows
            xf[tt] = ld8_lds(xw + row * 260 + kc * 32 + g * 8);
        }
#pragma unroll
        for (int ct = 0; ct < 2; ++ct) {
            bf16x8 aq = ld8_gb(wqb + ct * 4096 + kc * 512);
            bf16x8 ak = ld8_gb(wkb + ct * 4096 + kc * 512);
#pragma unroll
            for (int tt = 0; tt < 4; ++tt) {
                qa[ct][tt] = mfma_k32(aq, xf[tt], qa[ct][tt]);
                ka[ct][tt] = mfma_k32(ak, xf[tt], ka[ct][tt]);
            }
        }
    }

    // lane-local refragment: qf/kf[tt][ct]: row=li=tok(16tt+li), k=4g+j=ch(16ct+4g+j)
    bf16x4 qf[4][2], kf[4][2];
#pragma unroll
    for (int ct = 0; ct < 2; ++ct) {
        f32x4 bq = *(const f32x4*)(bqkv + h * 32 + 16 * ct + 4 * g);
        f32x4 bk = *(const f32x4*)(bqkv + 256 + h * 32 + 16 * ct + 4 * g);
#pragma unroll
        for (int tt = 0; tt < 4; ++tt)
#pragma unroll
            for (int r = 0; r < 4; ++r) {
                qf[tt][ct][r] = (__bf16)((qa[ct][tt][r] + bq[r]) * 0.17677669529663687f);
                kf[tt][ct][r] = (__bf16)(ka[ct][tt][r] + bk[r]);
            }
    }

    // ---- S^T = K . Q^T : s[kt][qt]: lane holds key=16kt+4g+r, q=16qt+li ----
    f32x4 s[4][4];
#pragma unroll
    for (int kt = 0; kt < 4; ++kt)
#pragma unroll
        for (int qt = 0; qt < 4; ++qt) {
            f32x4 acc = zf;
#pragma unroll
            for (int c2 = 0; c2 < 2; ++c2)
                acc = mfma_k16(kf[kt][c2], qf[qt][c2], acc);
            s[kt][qt] = acc;
        }

    unsigned inMk[4][4];
#pragma unroll
    for (int kt = 0; kt < 4; ++kt)
#pragma unroll
        for (int r = 0; r < 4; ++r)
            inMk[kt][r] = tinfo[16 * kt + 4 * g + r];

    const __bf16* tbh = tb + h * 170 + 84;
    bf16x4 pf[4][4];   // P frags [qt][kt]: row=li=q, k=4g+j=key
#pragma unroll
    for (int qt = 0; qt < 4; ++qt) {
        unsigned inN = tinfo[16 * qt + li];
        int codeN = (int)(inN & 0xffffu);
        float mx = -1e30f;
#pragma unroll
        for (int kt = 0; kt < 4; ++kt)
#pragma unroll
            for (int r = 0; r < 4; ++r) {
                unsigned inM = inMk[kt][r];
                float v = s[kt][qt][r] + (float)tbh[codeN - (int)(inM & 0xffffu)]
                        + ((((inN ^ inM) >> 16) != 0u) ? -100.f : 0.f);
                if (kt == 3 && (r > 0 || g > 0)) v = -30000.f;   // keys >= 49
                s[kt][qt][r] = v;
                mx = fmaxf(mx, v);
            }
        mx = fmaxf(mx, __shfl_xor(mx, 16));
        mx = fmaxf(mx, __shfl_xor(mx, 32));
        float sum = 0.f;
#pragma unroll
        for (int kt = 0; kt < 4; ++kt)
#pragma unroll
            for (int r = 0; r < 4; ++r) {
                float e = __expf(s[kt][qt][r] - mx);
                s[kt][qt][r] = e;
                sum += e;
            }
        sum += __shfl_xor(sum, 16);
        sum += __shfl_xor(sum, 32);
        float inv = 1.0f / sum;
#pragma unroll
        for (int kt = 0; kt < 4; ++kt) {
            bf16x4 pp;
#pragma unroll
            for (int r = 0; r < 4; ++r) pp[r] = (__bf16)(s[kt][qt][r] * inv);
            pf[qt][kt] = pp;
        }
    }

    // ---- V GEMM: V = X . Wv^T, A=x rows=tok, B=Wv rows=ch
    // va[tt][ct]: lane holds tok=16tt+4g+r, ch=16ct+li
    f32x4 va[4][2];
#pragma unroll
    for (int tt = 0; tt < 4; ++tt)
#pragma unroll
        for (int ct = 0; ct < 2; ++ct) va[tt][ct] = zf;
#pragma unroll
    for (int kc = 0; kc < 8; ++kc) {
        bf16x8 xf[4];
#pragma unroll
        for (int tt = 0; tt < 4; ++tt) {
            int row = 16 * tt + li; if (row > 48) row = 48;
            xf[tt] = ld8_lds(xw + row * 260 + kc * 32 + g * 8);
        }
#pragma unroll
        for (int ct = 0; ct < 2; ++ct) {
            bf16x8 bv = ld8_gb(wvb + ct * 4096 + kc * 512);
#pragma unroll
            for (int tt = 0; tt < 4; ++tt)
                va[tt][ct] = mfma_k32(xf[tt], bv, va[tt][ct]);
        }
    }
    bf16x4 vf[2][4];   // V^T frags [dt][kt]: row=li=d, k=4g+j=key
#pragma unroll
    for (int ct = 0; ct < 2; ++ct) {
        float bv = bqkv[512 + h * 32 + 16 * ct + li];
#pragma unroll
        for (int tt = 0; tt < 4; ++tt)
#pragma unroll
            for (int r = 0; r < 4; ++r)
                vf[ct][tt][r] = (__bf16)(va[tt][ct][r] + bv);
    }

    // ---- PV: out[qt][dt]: lane holds q=16qt+4g+r, d=16dt+li ----
    f32x4 oa[4][2];
#pragma unroll
    for (int qt = 0; qt < 4; ++qt)
#pragma unroll
        for (int dt = 0; dt < 2; ++dt) {
            f32x4 acc = zf;
#pragma unroll
            for (int kt = 0; kt < 4; ++kt)
                acc = mfma_k16(pf[qt][kt], vf[dt][kt], acc);
            oa[qt][dt] = acc;
        }

    // ---- ctx scatter -> cb ----
#pragma unroll
    for (int qt = 0; qt < 4; ++qt)
#pragma unroll
        for (int r = 0; r < 4; ++r) {
            int q = 16 * qt + 4 * g + r;
            if (q < 49) {
#pragma unroll
                for (int dt = 0; dt < 2; ++dt)
                    cb[q * 260 + 32 * h + 16 * dt + li] = (__bf16)oa[qt][dt][r];
            }
        }
    __syncthreads();   // barrier #2 (ctx complete)

    // ---- proj: 8 waves, wave = (pm: 32 rows, pn: 64 cols) ----
    const int pm = wid >> 2, pn = wid & 3;
    f32x4 pacc[2][4];
#pragma unroll
    for (int mt = 0; mt < 2; ++mt)
#pragma unroll
        for (int nt = 0; nt < 4; ++nt) pacc[mt][nt] = zf;

    const __bf16* wpb = wb + (size_t)(48 + 4 * pn) * 4096 + lane * 8;
#pragma unroll
    for (int kc = 0; kc < 8; ++kc) {
        bf16x8 a[2];
#pragma unroll
        for (int mt = 0; mt < 2; ++mt) {
            int row = 32 * pm + 16 * mt + li; if (row > 48) row = 48;
            a[mt] = ld8_lds(cb + row * 260 + kc * 32 + g * 8);
        }
#pragma unroll
        for (int nt = 0; nt < 4; ++nt) {
            bf16x8 bb = ld8_gb(wpb + nt * 4096 + kc * 512);
#pragma unroll
            for (int mt = 0; mt < 2; ++mt)
                pacc[mt][nt] = mfma_k32(a[mt], bb, pacc[mt][nt]);
        }
    }

    // ---- epilogue: bias + direct fp32 scatter (un-window + roll-back) ----
#pragma unroll
    for (int nt = 0; nt < 4; ++nt) {
        int o = 64 * pn + 16 * nt + li;
        float bias = pbias[o];
#pragma unroll
        for (int mt = 0; mt < 2; ++mt)
#pragma unroll
            for (int r = 0; r < 4; ++r) {
                int n = 32 * pm + 16 * mt + 4 * g + r;
                if (n < 49) {
                    int i = n / 7, j = n - 7 * i;
                    int rr = wh * 7 + i + 3; if (rr >= 56) rr -= 56;
                    int cc = ww * 7 + j + 3; if (cc >= 56) cc -= 56;
                    out[(((size_t)(b * 56 + rr) * 56 + cc) << 8) + o] =
                        pacc[mt][nt][r] + bias;
                }
            }
    }
}

extern "C" void kernel_launch(void* const* d_in, const int* in_sizes, int n_in,
                              void* d_out, int out_size, void* d_ws, size_t ws_size,
                              hipStream_t stream) {
    const float* x    = (const float*)d_in[0];
    const float* wqkv = (const float*)d_in[1];
    const float* bqkv = (const float*)d_in[2];
    const float* wp   = (const float*)d_in[3];
    const float* pb   = (const float*)d_in[4];
    const float* btab = (const float*)d_in[5];
    float* out = (float*)d_out;

    __bf16* wbuf = (__bf16*)d_ws;            // 262,144 bf16 = 512 KB
    k_w2bf<<<128, 256, 0, stream>>>(wqkv, wp, wbuf);
    k_swin<<<2048, 512, 0, stream>>>(x, wbuf, bqkv, btab, pb, out);
}

// Round 2
// 287.931 us; speedup vs baseline: 2.2320x; 1.6556x over previous
//
#include <hip/hip_runtime.h>

typedef float f32x4 __attribute__((ext_vector_type(4)));
typedef __bf16 bf16x4 __attribute__((ext_vector_type(4)));
typedef __bf16 bf16x8 __attribute__((ext_vector_type(8)));
typedef short s16x4 __attribute__((ext_vector_type(4)));

#define DEVI static __device__ __forceinline__

DEVI f32x4 mfma_k32(bf16x8 a, bf16x8 b, f32x4 c) {
    return __builtin_amdgcn_mfma_f32_16x16x32_bf16(a, b, c, 0, 0, 0);
}

union B4 { bf16x4 h; s16x4 s; };
// 16x16x16 bf16 MFMA: A/B frag k-index = (lane>>4)*4+j == C/D reg layout -> lane-local refragment
DEVI f32x4 mfma_k16(bf16x4 a, bf16x4 b, f32x4 c) {
    B4 ua, ub; ua.h = a; ub.h = b;
    return __builtin_amdgcn_mfma_f32_16x16x16bf16_1k(ua.s, ub.s, c, 0, 0, 0);
}

union F8 { bf16x8 v; bf16x4 h[2]; };

DEVI bf16x8 ld8_lds(const __bf16* p) {   // 16B fragment from LDS (two b64 reads)
    F8 f;
    f.h[0] = *(const bf16x4*)p;
    f.h[1] = *(const bf16x4*)(p + 4);
    return f.v;
}
DEVI bf16x8 ld8_gb(const __bf16* p) { return *(const bf16x8*)p; }  // 16B global
DEVI bf16x8 ldf8(const float* p) {       // 8 fp32 -> bf16x8
    f32x4 a = *(const f32x4*)p;
    f32x4 b = *(const f32x4*)(p + 4);
    F8 f;
#pragma unroll
    for (int j = 0; j < 4; ++j) {
        f.h[0][j] = (__bf16)a[j];
        f.h[1][j] = (__bf16)b[j];
    }
    return f.v;
}

// ---- pre-kernel: weights fp32 -> bf16, re-tiled into MFMA-fragment order ----
// layout: tile t (16 rows), kc (8 k-chunks of 32), lane l (64), j (8):
//   elem = W[t*16 + (l&15)][kc*32 + (l>>4)*8 + j]  -> flat ((t*8+kc)*64+l)*8+j
// tiles 0..47 = qkv rows 0..767, tiles 48..63 = proj rows 0..255.
__global__ __launch_bounds__(256) void k_w2bf(const float* __restrict__ wqkv,
                                              const float* __restrict__ wp,
                                              __bf16* __restrict__ o) {
    int i = blockIdx.x * 256 + threadIdx.x;      // 32768 threads, one per (t,kc,l)
    int t = i >> 9, kc = (i >> 6) & 7, l = i & 63;
    int row = t * 16 + (l & 15);
    int col = kc * 32 + (l >> 4) * 8;
    const float* src = (t < 48) ? (wqkv + row * 256 + col)
                                : (wp + (row - 768) * 256 + col);
    f32x4 a = *(const f32x4*)src;
    f32x4 b = *(const f32x4*)(src + 4);
    F8 f;
#pragma unroll
    for (int j = 0; j < 4; ++j) { f.h[0][j] = (__bf16)a[j]; f.h[1][j] = (__bf16)b[j]; }
    *(bf16x8*)(o + (size_t)i * 8) = f.v;
}

// ---------------------------------------------------------------------------
// Fused shifted-window attention. 1 block = 1 window, 8 waves = 8 heads.
// 2 barriers per block; attention fully register-resident per wave.
// VGPR budget: waves_per_eu(4) -> cap 128; peak live ~110 (S fused per-qt).
// ---------------------------------------------------------------------------
__global__ __launch_bounds__(512)
__attribute__((amdgpu_waves_per_eu(4))) void k_swin(
    const float* __restrict__ x,      // [32,56,56,256] fp32
    const __bf16* __restrict__ wb,    // tiled weights (ws): 64 tiles x 4096
    const float* __restrict__ bqkv,   // [768]
    const float* __restrict__ btab,   // [169,8]
    const float* __restrict__ pbias,  // [256]
    float* __restrict__ out)          // [32,56,56,256] fp32
{
    __shared__ __align__(16) unsigned char smem[53936];
    __bf16* xw = (__bf16*)(smem);                 // [49][260] staged window (bf16)
    __bf16* cb = (__bf16*)(smem + 25480);         // [49][260] ctx (attn output)
    __bf16* tb = (__bf16*)(smem + 50960);         // [8][170] bias table (transposed)
    unsigned* tinfo = (unsigned*)(smem + 53680);  // [64] token code|grp

    const int tid = threadIdx.x;
    const int wid = tid >> 6, lane = tid & 63;
    const int li = lane & 15, g = lane >> 4;
    const int blk = blockIdx.x;
    const int b = blk >> 6, wi = blk & 63;
    const int wh = wi >> 3, ww = wi & 7;
    const int h = wid;                            // wave == head

    // ---- stage shifted window (fp32 -> bf16) ----
    for (int c = tid; c < 49 * 32; c += 512) {
        int tok = c >> 5, part = c & 31;
        int i = tok / 7, j = tok - 7 * i;
        int r = wh * 7 + i + 3;  if (r >= 56) r -= 56;
        int cc = ww * 7 + j + 3; if (cc >= 56) cc -= 56;
        F8 f; f.v = ldf8(x + (((size_t)(b * 56 + r) * 56 + cc) << 8) + (part << 3));
        __bf16* dst = xw + tok * 260 + (part << 3);
        *(bf16x4*)dst = f.h[0];
        *(bf16x4*)(dst + 4) = f.h[1];
    }
    for (int c = tid; c < 169 * 8; c += 512) {       // bias table, transposed
        int idx = c >> 3, hh = c & 7;
        tb[hh * 170 + idx] = (__bf16)btab[c];
    }
    if (tid < 64) {
        int tok = tid;
        if (tok < 49) {
            int i = tok / 7, j = tok - 7 * i;
            unsigned rh = (wh == 7) ? (i < 4 ? 1u : 2u) : 0u;
            unsigned rw = (ww == 7) ? (j < 4 ? 1u : 2u) : 0u;
            tinfo[tok] = (unsigned)(13 * i + j) | ((rh * 3u + rw) << 16);
        } else {
            tinfo[tok] = 255u << 16;
        }
    }
    __syncthreads();   // barrier #1 (xw/tb/tinfo ready; read-only afterwards)

    const f32x4 zf = {0.f, 0.f, 0.f, 0.f};

    // ---- Q,K GEMM (head h): Q^T/K^T = W . X^T, A=W rows=out-ch, B=x rows=tok
    // acc[ct][tt]: lane holds ch = 16ct+4g+r, tok = 16tt+li
    f32x4 qa[2][4], ka[2][4];
#pragma unroll
    for (int ct = 0; ct < 2; ++ct)
#pragma unroll
        for (int tt = 0; tt < 4; ++tt) { qa[ct][tt] = zf; ka[ct][tt] = zf; }

    const __bf16* wqb = wb + (size_t)(2 * h) * 4096 + lane * 8;  // q tiles 2h,2h+1
    const __bf16* wkb = wqb + 16 * 4096;                          // k tiles +16
    const __bf16* wvb = wqb + 32 * 4096;                          // v tiles +32

#pragma unroll
    for (int kc = 0; kc < 8; ++kc) {
        bf16x8 xf[4];
#pragma unroll
        for (int tt = 0; tt < 4; ++tt) {
            int row = 16 * tt + li; if (row > 48) row = 48;   // clamp pad rows
            xf[tt] = ld8_lds(xw + row * 260 + kc * 32 + g * 8);
        }
#pragma unroll
        for (int ct = 0; ct < 2; ++ct) {
            bf16x8 aq = ld8_gb(wqb + ct * 4096 + kc * 512);
            bf16x8 ak = ld8_gb(wkb + ct * 4096 + kc * 512);
#pragma unroll
            for (int tt = 0; tt < 4; ++tt) {
                qa[ct][tt] = mfma_k32(aq, xf[tt], qa[ct][tt]);
                ka[ct][tt] = mfma_k32(ak, xf[tt], ka[ct][tt]);
            }
        }
    }

    // lane-local refragment: qf/kf[tt][ct]: row=li=tok(16tt+li), k=4g+j=ch(16ct+4g+j)
    bf16x4 qf[4][2], kf[4][2];
#pragma unroll
    for (int ct = 0; ct < 2; ++ct) {
        f32x4 bq = *(const f32x4*)(bqkv + h * 32 + 16 * ct + 4 * g);
        f32x4 bk = *(const f32x4*)(bqkv + 256 + h * 32 + 16 * ct + 4 * g);
#pragma unroll
        for (int tt = 0; tt < 4; ++tt)
#pragma unroll
            for (int r = 0; r < 4; ++r) {
                qf[tt][ct][r] = (__bf16)((qa[ct][tt][r] + bq[r]) * 0.17677669529663687f);
                kf[tt][ct][r] = (__bf16)(ka[ct][tt][r] + bk[r]);
            }
    }

    unsigned inMk[4][4];
#pragma unroll
    for (int kt = 0; kt < 4; ++kt)
#pragma unroll
        for (int r = 0; r < 4; ++r)
            inMk[kt][r] = tinfo[16 * kt + 4 * g + r];

    // ---- fused S + softmax, one q-tile at a time (16 f32 live, not 64) ----
    const __bf16* tbh = tb + h * 170 + 84;
    bf16x4 pf[4][4];   // P frags [qt][kt]: row=li=q, k=4g+j=key
#pragma unroll
    for (int qt = 0; qt < 4; ++qt) {
        f32x4 sv[4];   // S^T frags: lane holds key=16kt+4g+r, q=16qt+li
#pragma unroll
        for (int kt = 0; kt < 4; ++kt) {
            f32x4 acc = zf;
            acc = mfma_k16(kf[kt][0], qf[qt][0], acc);
            acc = mfma_k16(kf[kt][1], qf[qt][1], acc);
            sv[kt] = acc;
        }
        unsigned inN = tinfo[16 * qt + li];
        int codeN = (int)(inN & 0xffffu);
        float mx = -1e30f;
#pragma unroll
        for (int kt = 0; kt < 4; ++kt)
#pragma unroll
            for (int r = 0; r < 4; ++r) {
                unsigned inM = inMk[kt][r];
                float v = sv[kt][r] + (float)tbh[codeN - (int)(inM & 0xffffu)]
                        + ((((inN ^ inM) >> 16) != 0u) ? -100.f : 0.f);
                if (kt == 3 && (r > 0 || g > 0)) v = -30000.f;   // keys >= 49
                sv[kt][r] = v;
                mx = fmaxf(mx, v);
            }
        mx = fmaxf(mx, __shfl_xor(mx, 16));
        mx = fmaxf(mx, __shfl_xor(mx, 32));
        float sum = 0.f;
#pragma unroll
        for (int kt = 0; kt < 4; ++kt)
#pragma unroll
            for (int r = 0; r < 4; ++r) {
                float e = __expf(sv[kt][r] - mx);
                sv[kt][r] = e;
                sum += e;
            }
        sum += __shfl_xor(sum, 16);
        sum += __shfl_xor(sum, 32);
        float inv = 1.0f / sum;
#pragma unroll
        for (int kt = 0; kt < 4; ++kt) {
            bf16x4 pp;
#pragma unroll
            for (int r = 0; r < 4; ++r) pp[r] = (__bf16)(sv[kt][r] * inv);
            pf[qt][kt] = pp;
        }
    }
    __builtin_amdgcn_sched_barrier(0);   // fence: keep V-GEMM out of softmax pressure

    // ---- V GEMM: V = X . Wv^T, A=x rows=tok, B=Wv rows=ch
    // va[tt][ct]: lane holds tok=16tt+4g+r, ch=16ct+li
    f32x4 va[4][2];
#pragma unroll
    for (int tt = 0; tt < 4; ++tt)
#pragma unroll
        for (int ct = 0; ct < 2; ++ct) va[tt][ct] = zf;
#pragma unroll
    for (int kc = 0; kc < 8; ++kc) {
        bf16x8 xf[4];
#pragma unroll
        for (int tt = 0; tt < 4; ++tt) {
            int row = 16 * tt + li; if (row > 48) row = 48;
            xf[tt] = ld8_lds(xw + row * 260 + kc * 32 + g * 8);
        }
#pragma unroll
        for (int ct = 0; ct < 2; ++ct) {
            bf16x8 bv = ld8_gb(wvb + ct * 4096 + kc * 512);
#pragma unroll
            for (int tt = 0; tt < 4; ++tt)
                va[tt][ct] = mfma_k32(xf[tt], bv, va[tt][ct]);
        }
    }
    bf16x4 vf[2][4];   // V^T frags [dt][kt]: row=li=d, k=4g+j=key
#pragma unroll
    for (int ct = 0; ct < 2; ++ct) {
        float bv = bqkv[512 + h * 32 + 16 * ct + li];
#pragma unroll
        for (int tt = 0; tt < 4; ++tt)
#pragma unroll
            for (int r = 0; r < 4; ++r)
                vf[ct][tt][r] = (__bf16)(va[tt][ct][r] + bv);
    }

    // ---- PV: out[qt][dt]: lane holds q=16qt+4g+r, d=16dt+li ----
    f32x4 oa[4][2];
#pragma unroll
    for (int qt = 0; qt < 4; ++qt)
#pragma unroll
        for (int dt = 0; dt < 2; ++dt) {
            f32x4 acc = zf;
#pragma unroll
            for (int kt = 0; kt < 4; ++kt)
                acc = mfma_k16(pf[qt][kt], vf[dt][kt], acc);
            oa[qt][dt] = acc;
        }

    // ---- ctx scatter -> cb ----
#pragma unroll
    for (int qt = 0; qt < 4; ++qt)
#pragma unroll
        for (int r = 0; r < 4; ++r) {
            int q = 16 * qt + 4 * g + r;
            if (q < 49) {
#pragma unroll
                for (int dt = 0; dt < 2; ++dt)
                    cb[q * 260 + 32 * h + 16 * dt + li] = (__bf16)oa[qt][dt][r];
            }
        }
    __syncthreads();   // barrier #2 (ctx complete)

    // ---- proj: 8 waves, wave = (pm: 32 rows, pn: 64 cols) ----
    const int pm = wid >> 2, pn = wid & 3;
    f32x4 pacc[2][4];
#pragma unroll
    for (int mt = 0; mt < 2; ++mt)
#pragma unroll
        for (int nt = 0; nt < 4; ++nt) pacc[mt][nt] = zf;

    const __bf16* wpb = wb + (size_t)(48 + 4 * pn) * 4096 + lane * 8;
#pragma unroll
    for (int kc = 0; kc < 8; ++kc) {
        bf16x8 a[2];
#pragma unroll
        for (int mt = 0; mt < 2; ++mt) {
            int row = 32 * pm + 16 * mt + li; if (row > 48) row = 48;
            a[mt] = ld8_lds(cb + row * 260 + kc * 32 + g * 8);
        }
#pragma unroll
        for (int nt = 0; nt < 4; ++nt) {
            bf16x8 bb = ld8_gb(wpb + nt * 4096 + kc * 512);
#pragma unroll
            for (int mt = 0; mt < 2; ++mt)
                pacc[mt][nt] = mfma_k32(a[mt], bb, pacc[mt][nt]);
        }
    }

    // ---- epilogue: bias + direct fp32 scatter (un-window + roll-back) ----
#pragma unroll
    for (int nt = 0; nt < 4; ++nt) {
        int o = 64 * pn + 16 * nt + li;
        float bias = pbias[o];
#pragma unroll
        for (int mt = 0; mt < 2; ++mt)
#pragma unroll
            for (int r = 0; r < 4; ++r) {
                int n = 32 * pm + 16 * mt + 4 * g + r;
                if (n < 49) {
                    int i = n / 7, j = n - 7 * i;
                    int rr = wh * 7 + i + 3; if (rr >= 56) rr -= 56;
                    int cc = ww * 7 + j + 3; if (cc >= 56) cc -= 56;
                    out[(((size_t)(b * 56 + rr) * 56 + cc) << 8) + o] =
                        pacc[mt][nt][r] + bias;
                }
            }
    }
}

extern "C" void kernel_launch(void* const* d_in, const int* in_sizes, int n_in,
                              void* d_out, int out_size, void* d_ws, size_t ws_size,
                              hipStream_t stream) {
    const float* x    = (const float*)d_in[0];
    const float* wqkv = (const float*)d_in[1];
    const float* bqkv = (const float*)d_in[2];
    const float* wp   = (const float*)d_in[3];
    const float* pb   = (const float*)d_in[4];
    const float* btab = (const float*)d_in[5];
    float* out = (float*)d_out;

    __bf16* wbuf = (__bf16*)d_ws;            // 262,144 bf16 = 512 KB
    k_w2bf<<<128, 256, 0, stream>>>(wqkv, wp, wbuf);
    k_swin<<<2048, 512, 0, stream>>>(x, wbuf, bqkv, btab, pb, out);
}